// Round 3
// baseline (1215.843 us; speedup 1.0000x reference)
//
#include <hip/hip_runtime.h>
#include <stdint.h>
#include <stddef.h>

// Problem constants
#define N_Q 256        // queries
#define M_D 50000      // dataset rows
#define K_D 3072       // feature dim
#define MT 64          // dataset rows (output cols) per workgroup in scores GEMM
#define NKT 96         // K steps of 32
#define CAND_CAP 128   // max candidates per row
#define WINDOW 9.0f    // raw-score candidate window (36 logits; bf16 err bound ~0.6)
#define SPLIT 8        // scan blocks per score row

typedef short bf16x8 __attribute__((ext_vector_type(8)));   // 8 bf16 = 4 VGPRs
typedef float f32x4 __attribute__((ext_vector_type(4)));

// fp32 -> bf16 round-to-nearest-even (bitwise identical to prior rounds)
static __device__ __forceinline__ unsigned short f2bf(float f) {
    unsigned int u = __float_as_uint(f);
    u += 0x7fffu + ((u >> 16) & 1u);
    return (unsigned short)(u >> 16);
}

// monotone float -> sortable uint (for atomicMax on float values)
static __device__ __forceinline__ unsigned fkey(float f) {
    int i = __float_as_int(f);
    return (i < 0) ? ~(unsigned)i : ((unsigned)i | 0x80000000u);
}
static __device__ __forceinline__ float funkey(unsigned u) {
    int i = (u & 0x80000000u) ? (int)(u & 0x7fffffffu) : ~(int)u;
    return __int_as_float(i);
}

// ---------------------------------------------------------------------------
// K0: convert x [256x3072] fp32 -> bf16; also zero rowmax keys + cand counts
// ---------------------------------------------------------------------------
__global__ __launch_bounds__(256) void cvt_x_kernel(const float* __restrict__ x,
                                                    short* __restrict__ xb,
                                                    unsigned* __restrict__ rowmax_u,
                                                    int* __restrict__ ccnt) {
    int i = (blockIdx.x * 256 + threadIdx.x) * 4;   // grid covers exactly 786432
    float4 f = *(const float4*)(x + i);
    ushort4 o;
    o.x = f2bf(f.x); o.y = f2bf(f.y); o.z = f2bf(f.z); o.w = f2bf(f.w);
    *(ushort4*)(xb + i) = o;
    if (blockIdx.x == 0) {
        rowmax_u[threadIdx.x] = 0u;   // smallest key; overwritten by gemm atomicMax
        ccnt[threadIdx.x] = 0;
    }
}

// ---------------------------------------------------------------------------
// K1: scores[n][m] = sum_k xb[n][k] * bf16(dataset[m][k])   (raw dot, no temp)
// ZERO-LDS design: MFMA fragments are loaded straight from global memory.
//   A frag (xb, bf16, L2-resident: 1.5MB reused by all 782 blocks): 16B/lane,
//   B frag (dset fp32 -> RNE bf16 in regs): 32B/lane.
//   Per wave-load the 64 lanes cover 16 rows x 128B contiguous -> full cache
//   lines. No barriers, no waitcnt drains, no LDS pipe; register double-buffer
//   (a0/b0, a1/b1) overlaps next-K loads with current-K MFMAs.
// Epilogue additionally reduces per-row block max (shfl_xor over the 16
// column lanes) and atomicMax's a sortable-uint key -> rowmax pass deleted.
// ---------------------------------------------------------------------------
template<bool EDGE>
static __device__ __forceinline__ void gemm_body(const short* __restrict__ xb,
                                                 const float* __restrict__ dset,
                                                 float* __restrict__ scores,
                                                 unsigned* __restrict__ rowmax_u,
                                                 int m0) {
    const int tid = threadIdx.x;
    const int w = tid >> 6;        // wave 0..3: output rows w*64..w*64+63
    const int l = tid & 63;
    const int rA = l & 15;         // fragment row-within-16
    const int kk = (l >> 4) * 8;   // lane's k-offset within the 32-K step

    // A fragment pointers, one per ai (16-row group)
    const short* pA[4];
#pragma unroll
    for (int ai = 0; ai < 4; ++ai)
        pA[ai] = xb + (size_t)(w * 64 + ai * 16 + rA) * K_D + kk;

    // B fragment pointers, one per bj (16-col group); clamp rows at M edge
    const float* pB[4];
    bool vB[4];
#pragma unroll
    for (int bj = 0; bj < 4; ++bj) {
        int m = m0 + bj * 16 + rA;
        vB[bj] = (m < M_D);
        if (EDGE && m >= M_D) m = M_D - 1;
        pB[bj] = dset + (size_t)m * K_D + kk;
    }

    f32x4 acc[4][4];
#pragma unroll
    for (int i = 0; i < 4; ++i)
#pragma unroll
        for (int j = 0; j < 4; ++j)
            acc[i][j] = (f32x4){0.f, 0.f, 0.f, 0.f};

    bf16x8 a0[4], a1[4];           // A double-buffer (16B/lane each kt)
    float4 b0[8], b1[8];           // B raw fp32 double-buffer (32B/lane each kt)

    auto loadA = [&](bf16x8* dst, int kt) {
#pragma unroll
        for (int ai = 0; ai < 4; ++ai)
            dst[ai] = *(const bf16x8*)(pA[ai] + kt * 32);
    };
    auto loadB = [&](float4* dst, int kt) {
#pragma unroll
        for (int bj = 0; bj < 4; ++bj) {
            dst[bj * 2]     = *(const float4*)(pB[bj] + kt * 32);
            dst[bj * 2 + 1] = *(const float4*)(pB[bj] + kt * 32 + 4);
        }
    };
    auto step = [&](const bf16x8* av, const float4* bv) {
        bf16x8 bfr[4];
#pragma unroll
        for (int bj = 0; bj < 4; ++bj) {
            float4 lo = bv[bj * 2], hi = bv[bj * 2 + 1];
            bf16x8 p;
            p[0] = (short)f2bf(lo.x); p[1] = (short)f2bf(lo.y);
            p[2] = (short)f2bf(lo.z); p[3] = (short)f2bf(lo.w);
            p[4] = (short)f2bf(hi.x); p[5] = (short)f2bf(hi.y);
            p[6] = (short)f2bf(hi.z); p[7] = (short)f2bf(hi.w);
            if (EDGE && !vB[bj]) p = (bf16x8){0, 0, 0, 0, 0, 0, 0, 0};
            bfr[bj] = p;
        }
#pragma unroll
        for (int ai = 0; ai < 4; ++ai)
#pragma unroll
            for (int bj = 0; bj < 4; ++bj)
                acc[ai][bj] = __builtin_amdgcn_mfma_f32_16x16x32_bf16(
                    av[ai], bfr[bj], acc[ai][bj], 0, 0, 0);
    };

    loadA(a0, 0); loadB(b0, 0);
    loadA(a1, 1); loadB(b1, 1);
    for (int kt = 0; kt < NKT; kt += 2) {
        step(a0, b0);
        if (kt + 2 < NKT) { loadA(a0, kt + 2); loadB(b0, kt + 2); }
        step(a1, b1);
        if (kt + 3 < NKT) { loadA(a1, kt + 3); loadB(b1, kt + 3); }
    }

    // ---- fused per-row max: reduce over bj + 16 column lanes, atomicMax key
    const int crow = (l >> 4) * 4;
    const int ccol = l & 15;
#pragma unroll
    for (int ai = 0; ai < 4; ++ai) {
#pragma unroll
        for (int r = 0; r < 4; ++r) {
            float mx = -3.0e38f;
#pragma unroll
            for (int bj = 0; bj < 4; ++bj) {
                float v = acc[ai][bj][r];
                if (!EDGE || (m0 + bj * 16 + ccol) < M_D) mx = fmaxf(mx, v);
            }
#pragma unroll
            for (int off = 1; off < 16; off <<= 1)
                mx = fmaxf(mx, __shfl_xor(mx, off));
            if (ccol == 0)
                atomicMax(rowmax_u + (w * 64 + ai * 16 + crow + r), fkey(mx));
        }
    }

    // ---- store scores: C/D layout col = l&15, row = (l>>4)*4 + r [m89]
#pragma unroll
    for (int ai = 0; ai < 4; ++ai) {
#pragma unroll
        for (int bj = 0; bj < 4; ++bj) {
            int m = m0 + bj * 16 + ccol;
            if (!EDGE || m < M_D) {
#pragma unroll
                for (int r = 0; r < 4; ++r) {
                    int n = w * 64 + ai * 16 + crow + r;
                    scores[(size_t)n * M_D + m] = acc[ai][bj][r];
                }
            }
        }
    }
}

__global__ __launch_bounds__(256, 2) void gemm_scores(const short* __restrict__ xb,
                                                      const float* __restrict__ dset,
                                                      float* __restrict__ scores,
                                                      unsigned* __restrict__ rowmax_u) {
    const int m0 = blockIdx.x * MT;
    if (m0 + MT <= M_D)
        gemm_body<false>(xb, dset, scores, rowmax_u, m0);
    else
        gemm_body<true>(xb, dset, scores, rowmax_u, m0);
}

// ---------------------------------------------------------------------------
// K2: per (row, segment): collect candidates with s >= rowmax - WINDOW
//     (rowmax comes from the GEMM's fused atomicMax; ccnt pre-zeroed in K0)
// ---------------------------------------------------------------------------
__global__ __launch_bounds__(256) void collect_kernel(const float* __restrict__ scores,
                                                      const unsigned* __restrict__ rowmax_u,
                                                      int* __restrict__ cidx,
                                                      int* __restrict__ ccnt) {
    const int n = blockIdx.x >> 3;
    const int s = blockIdx.x & 7;
    const int tid = threadIdx.x;

    const float thr = funkey(rowmax_u[n]) - WINDOW;

    const float4* row4 = (const float4*)(scores + (size_t)n * M_D);
    const int start = s * 1563;                 // 1563*8 = 12504 >= 12500
    int end = start + 1563; if (end > M_D / 4) end = M_D / 4;

    for (int i = start + tid; i < end; i += 256) {
        float4 v = row4[i];
        if (v.x >= thr || v.y >= thr || v.z >= thr || v.w >= thr) {
            float e[4] = {v.x, v.y, v.z, v.w};
#pragma unroll
            for (int j = 0; j < 4; ++j) {
                if (e[j] >= thr) {
                    int p = atomicAdd(&ccnt[n], 1);   // rare (~1-5/row)
                    if (p < CAND_CAP) cidx[n * CAND_CAP + p] = i * 4 + j;
                }
            }
        }
    }
}

// ---------------------------------------------------------------------------
// K3: per row: exact fp32 logits for candidates (wave-parallel), softmax,
//     sparse weighted sum
// ---------------------------------------------------------------------------
__global__ __launch_bounds__(256) void finalize_rows(const float* __restrict__ x,
                                                     const float* __restrict__ dset,
                                                     const int* __restrict__ cidx,
                                                     const int* __restrict__ ccnt,
                                                     float* __restrict__ out) {
    const int n = blockIdx.x;
    const int tid = threadIdx.x;
    const int w = tid >> 6, l = tid & 63;
    int cnt = ccnt[n]; if (cnt > CAND_CAP) cnt = CAND_CAP;

    __shared__ float L[CAND_CAP];
    const float4* xr4 = (const float4*)(x + (size_t)n * K_D);

    // wave w handles candidates w, w+4, ... (no per-candidate barriers)
    for (int c = w; c < cnt; c += 4) {
        const float4* dr4 = (const float4*)(dset + (size_t)cidx[n * CAND_CAP + c] * K_D);
        float p = 0.f;
        for (int j = l; j < K_D / 4; j += 64) {      // 12 iters
            float4 a = xr4[j], b = dr4[j];
            p += a.x * b.x + a.y * b.y + a.z * b.z + a.w * b.w;
        }
#pragma unroll
        for (int off = 32; off > 0; off >>= 1) p += __shfl_down(p, off);
        if (l == 0) L[c] = 4.0f * p;                 // logit = dot / noise_var
    }
    __syncthreads();

    // softmax over candidates (cnt tiny; L becomes weights)
    if (tid == 0) {
        float mx = -3.0e38f;
        for (int c = 0; c < cnt; ++c) mx = fmaxf(mx, L[c]);
        float s = 0.f;
        for (int c = 0; c < cnt; ++c) { float e = expf(L[c] - mx); L[c] = e; s += e; }
        float inv = 1.0f / s;
        for (int c = 0; c < cnt; ++c) L[c] *= inv;
    }
    __syncthreads();

    // out[n][:] = sum_c w_c * dataset[cand_c][:]
    float4* out4 = (float4*)(out + (size_t)n * K_D);
    for (int j = tid; j < K_D / 4; j += 256) {
        float4 o = {0.f, 0.f, 0.f, 0.f};
        for (int c = 0; c < cnt; ++c) {
            float wc = L[c];
            float4 d = *(const float4*)(dset + (size_t)cidx[n * CAND_CAP + c] * K_D + j * 4);
            o.x += wc * d.x; o.y += wc * d.y; o.z += wc * d.z; o.w += wc * d.w;
        }
        out4[j] = o;
    }
}

// ---------------------------------------------------------------------------
extern "C" void kernel_launch(void* const* d_in, const int* in_sizes, int n_in,
                              void* d_out, int out_size, void* d_ws, size_t ws_size,
                              hipStream_t stream) {
    const float* x = (const float*)d_in[0];      // [256,3,32,32]
    const float* dset = (const float*)d_in[1];   // [50000,3,32,32]
    float* out = (float*)d_out;

    // workspace layout (all offsets 256B-aligned):
    //   xb        : 256*3072 bf16   = 1,572,864 B
    //   scores    : 256*50000 fp32  = 51,200,000 B
    //   rowmax_u  : 256 uint        = 1,024 B
    //   cidx      : 256*128 int     = 131,072 B
    //   ccnt      : 256 int         = 1,024 B
    char* ws = (char*)d_ws;
    short* xb          = (short*)ws;
    float* scores      = (float*)(ws + 1572864);
    unsigned* rowmax_u = (unsigned*)(ws + 1572864 + 51200000);
    int* cidx          = (int*)(ws + 1572864 + 51200000 + 1024);
    int* ccnt          = (int*)(ws + 1572864 + 51200000 + 1024 + 131072);

    cvt_x_kernel<<<768, 256, 0, stream>>>(x, xb, rowmax_u, ccnt);
    gemm_scores<<<(M_D + MT - 1) / MT, 256, 0, stream>>>(xb, dset, scores, rowmax_u);
    collect_kernel<<<N_Q * SPLIT, 256, 0, stream>>>(scores, rowmax_u, cidx, ccnt);
    finalize_rows<<<N_Q, 256, 0, stream>>>(x, dset, cidx, ccnt, out);
}

// Round 5
// 1215.496 us; speedup vs baseline: 1.0003x; 1.0003x over previous
//
#include <hip/hip_runtime.h>
#include <stdint.h>
#include <stddef.h>

// Problem constants
#define N_Q 256        // queries
#define M_D 50000      // dataset rows
#define K_D 3072       // feature dim
#define MT 64          // dataset rows (output cols) per workgroup in scores GEMM
#define BK 32          // K elements per step
#define NKT 96         // K steps
#define CAND_CAP 128   // max candidates per row
#define WINDOW 9.0f    // raw-score candidate window (36 logits; bf16 err bound ~0.6)
#define SPLIT 8        // scan blocks per score row

typedef short bf16x8 __attribute__((ext_vector_type(8)));   // 8 bf16 = 4 VGPRs
typedef float f32x4 __attribute__((ext_vector_type(4)));

// fp32 -> bf16 round-to-nearest-even (bitwise identical to prior rounds)
static __device__ __forceinline__ unsigned short f2bf(float f) {
    unsigned int u = __float_as_uint(f);
    u += 0x7fffu + ((u >> 16) & 1u);
    return (unsigned short)(u >> 16);
}

// monotone float -> sortable uint (for atomicMax on float values)
static __device__ __forceinline__ unsigned fkey(float f) {
    int i = __float_as_int(f);
    return (i < 0) ? ~(unsigned)i : ((unsigned)i | 0x80000000u);
}
static __device__ __forceinline__ float funkey(unsigned u) {
    int i = (u & 0x80000000u) ? (int)(u & 0x7fffffffu) : ~(int)u;
    return __int_as_float(i);
}

// async global->LDS, 16B/lane; LDS dest = wave-uniform base + lane*16 (m104)
static __device__ __forceinline__ void load_lds16(const void* g, void* l) {
    __builtin_amdgcn_global_load_lds(
        (const __attribute__((address_space(1))) void*)g,
        (__attribute__((address_space(3))) void*)l, 16, 0, 0);
}

// ---------------------------------------------------------------------------
// K0: convert x [256x3072] fp32 -> bf16; also zero rowmax keys + cand counts
// ---------------------------------------------------------------------------
__global__ __launch_bounds__(256) void cvt_x_kernel(const float* __restrict__ x,
                                                    short* __restrict__ xb,
                                                    unsigned* __restrict__ rowmax_u,
                                                    int* __restrict__ ccnt) {
    int i = (blockIdx.x * 256 + threadIdx.x) * 4;   // grid covers exactly 786432
    float4 f = *(const float4*)(x + i);
    ushort4 o;
    o.x = f2bf(f.x); o.y = f2bf(f.y); o.z = f2bf(f.z); o.w = f2bf(f.w);
    *(ushort4*)(xb + i) = o;
    if (blockIdx.x == 0) {
        rowmax_u[threadIdx.x] = 0u;   // smallest key; set by gemm atomicMax
        ccnt[threadIdx.x] = 0;
    }
}

// ---------------------------------------------------------------------------
// K1: scores[n][m] = sum_k xb[n][k] * bf16(dataset[m][k])
// 2-phase double-buffered LDS GEMM (T3 "minimum 2-phase", m230-V0 pattern):
//   - per K-step: issue global_load_lds for tile kt+1 FIRST, then
//     ds_read+convert+MFMA on tile kt, then ONE __syncthreads() (its
//     vmcnt(0) drain overlaps the whole compute phase -> HBM latency hidden;
//     loads live in the HW queue, zero VGPR -> compiler can't deschedule).
//   - A (xb bf16, L2-resident): 16 KB/step via 4 gload_lds, source pre-
//     swizzled chunk^=(row&3) (rule #21), frag ds_read_b128 4-way (minor).
//   - B (dset fp32, HBM-cold, read ONCE): 8 KB/step via 2 gload_lds, source
//     pre-swizzled chunk^=(row&7) -> frag reads 2-way (free); fp32->bf16
//     RNE convert at frag-read (32 f2bf/wave/step, hides under MFMA).
// Per-CU arithmetic: 3 blocks/CU; per step-slot HBM = 24 KB (~2400 cyc at
// 10.3 B/cyc/CU) vs LDS ~1300 cyc vs MFMA ~230 cyc -> HBM-streaming-bound.
// Fused per-row max epilogue (shfl_xor + sortable-uint atomicMax).
// Accumulation order identical to prior rounds -> scores bitwise identical.
// ---------------------------------------------------------------------------
template<bool EDGE>
static __device__ __forceinline__ void gemm_body(const short* __restrict__ xb,
                                                 const float* __restrict__ dset,
                                                 float* __restrict__ scores,
                                                 unsigned* __restrict__ rowmax_u,
                                                 int m0) {
    // double-buffered tiles: A 2x16KB (256 rows x 32 bf16), B 2x8KB (64 x 32 fp32)
    __shared__ __align__(16) short sA[2][N_Q * BK];
    __shared__ __align__(16) float sB[2][MT * BK];

    const int tid = threadIdx.x;
    const int w = tid >> 6;        // wave 0..3: output rows w*64..w*64+63
    const int l = tid & 63;

    // ---- A staging: chunk id = g*256+tid (g=0..3); row R=id>>2, slot S=id&3,
    //      source chunk C = S ^ (R&3). g adds 64 to R (R&3 invariant).
    const int aR = tid >> 2;                       // row for g=0
    const int aC = (tid & 3) ^ (aR & 3);
    const short* aSrc = xb + (size_t)aR * K_D + aC * 8;

    // ---- B staging: chunk id = g*256+tid (g=0..1); row R=id>>3, slot S=id&7,
    //      source chunk C = S ^ (R&7). g adds 32 to R (R&7 invariant).
    const int bR = tid >> 3;                       // row for g=0 (0..31)
    const int bC = (tid & 7) ^ (bR & 7);
    int br0 = m0 + bR, br1 = m0 + bR + 32;
    if (EDGE) { if (br0 >= M_D) br0 = M_D - 1; if (br1 >= M_D) br1 = M_D - 1; }
    const float* bSrc0 = dset + (size_t)br0 * K_D + bC * 4;
    const float* bSrc1 = dset + (size_t)br1 * K_D + bC * 4;

    auto stage = [&](int p, int kt) {
#pragma unroll
        for (int g = 0; g < 4; ++g)     // A: wave-uniform LDS base g*2048+w*512
            load_lds16(aSrc + (size_t)g * 64 * K_D + kt * 32,
                       &sA[p][g * 2048 + w * 512]);
        load_lds16(bSrc0 + kt * 32, &sB[p][w * 256]);          // B g=0
        load_lds16(bSrc1 + kt * 32, &sB[p][1024 + w * 256]);   // B g=1
    };

    // ---- fragment read offsets (swizzled)
    const int rA = l & 15;         // row-within-16
    const int kq = l >> 4;         // lane's 16B chunk (k-offset kq*8)
    const int aOff = rA * 32 + ((kq ^ (rA & 3)) << 3);              // shorts
    const int bOff0 = rA * 32 + (((2 * kq) ^ (rA & 7)) << 2);       // floats
    const int bOff1 = rA * 32 + (((2 * kq + 1) ^ (rA & 7)) << 2);

    f32x4 acc[4][4];
#pragma unroll
    for (int i = 0; i < 4; ++i)
#pragma unroll
        for (int j = 0; j < 4; ++j)
            acc[i][j] = (f32x4){0.f, 0.f, 0.f, 0.f};

    stage(0, 0);
    __syncthreads();

    int p = 0;
    for (int kt = 0; kt < NKT; ++kt) {
        if (kt + 1 < NKT) stage(p ^ 1, kt + 1);   // issue BEFORE compute

        bf16x8 af[4], bfr[4];
#pragma unroll
        for (int ai = 0; ai < 4; ++ai)
            af[ai] = *(const bf16x8*)&sA[p][(w * 64 + ai * 16) * 32 + aOff];
#pragma unroll
        for (int bj = 0; bj < 4; ++bj) {
            float4 lo = *(const float4*)&sB[p][bj * 512 + bOff0];
            float4 hi = *(const float4*)&sB[p][bj * 512 + bOff1];
            bf16x8 q;
            q[0] = (short)f2bf(lo.x); q[1] = (short)f2bf(lo.y);
            q[2] = (short)f2bf(lo.z); q[3] = (short)f2bf(lo.w);
            q[4] = (short)f2bf(hi.x); q[5] = (short)f2bf(hi.y);
            q[6] = (short)f2bf(hi.z); q[7] = (short)f2bf(hi.w);
            bfr[bj] = q;
        }
#pragma unroll
        for (int ai = 0; ai < 4; ++ai)
#pragma unroll
            for (int bj = 0; bj < 4; ++bj)
                acc[ai][bj] = __builtin_amdgcn_mfma_f32_16x16x32_bf16(
                    af[ai], bfr[bj], acc[ai][bj], 0, 0, 0);

        __syncthreads();    // drains stage(kt+1) — overlapped with compute above
        p ^= 1;
    }

    // ---- fused per-row max: reduce over bj + 16 column lanes, atomicMax key
    const int crow = (l >> 4) * 4;
    const int ccol = l & 15;
#pragma unroll
    for (int ai = 0; ai < 4; ++ai) {
#pragma unroll
        for (int r = 0; r < 4; ++r) {
            float mx = -3.0e38f;
#pragma unroll
            for (int bj = 0; bj < 4; ++bj) {
                float v = acc[ai][bj][r];
                if (!EDGE || (m0 + bj * 16 + ccol) < M_D) mx = fmaxf(mx, v);
            }
#pragma unroll
            for (int off = 1; off < 16; off <<= 1)
                mx = fmaxf(mx, __shfl_xor(mx, off));
            if (ccol == 0)
                atomicMax(rowmax_u + (w * 64 + ai * 16 + crow + r), fkey(mx));
        }
    }

    // ---- store scores: C/D layout col = l&15, row = (l>>4)*4 + r [m89]
#pragma unroll
    for (int ai = 0; ai < 4; ++ai) {
#pragma unroll
        for (int bj = 0; bj < 4; ++bj) {
            int m = m0 + bj * 16 + ccol;
            if (!EDGE || m < M_D) {
#pragma unroll
                for (int r = 0; r < 4; ++r) {
                    int n = w * 64 + ai * 16 + crow + r;
                    scores[(size_t)n * M_D + m] = acc[ai][bj][r];
                }
            }
        }
    }
}

__global__ __launch_bounds__(256) void gemm_scores(const short* __restrict__ xb,
                                                   const float* __restrict__ dset,
                                                   float* __restrict__ scores,
                                                   unsigned* __restrict__ rowmax_u) {
    const int m0 = blockIdx.x * MT;
    if (m0 + MT <= M_D)
        gemm_body<false>(xb, dset, scores, rowmax_u, m0);
    else
        gemm_body<true>(xb, dset, scores, rowmax_u, m0);
}

// ---------------------------------------------------------------------------
// K2: per (row, segment): collect candidates with s >= rowmax - WINDOW
// ---------------------------------------------------------------------------
__global__ __launch_bounds__(256) void collect_kernel(const float* __restrict__ scores,
                                                      const unsigned* __restrict__ rowmax_u,
                                                      int* __restrict__ cidx,
                                                      int* __restrict__ ccnt) {
    const int n = blockIdx.x >> 3;
    const int s = blockIdx.x & 7;
    const int tid = threadIdx.x;

    const float thr = funkey(rowmax_u[n]) - WINDOW;

    const float4* row4 = (const float4*)(scores + (size_t)n * M_D);
    const int start = s * 1563;                 // 1563*8 = 12504 >= 12500
    int end = start + 1563; if (end > M_D / 4) end = M_D / 4;

    for (int i = start + tid; i < end; i += 256) {
        float4 v = row4[i];
        if (v.x >= thr || v.y >= thr || v.z >= thr || v.w >= thr) {
            float e[4] = {v.x, v.y, v.z, v.w};
#pragma unroll
            for (int j = 0; j < 4; ++j) {
                if (e[j] >= thr) {
                    int p = atomicAdd(&ccnt[n], 1);   // rare (~1-5/row)
                    if (p < CAND_CAP) cidx[n * CAND_CAP + p] = i * 4 + j;
                }
            }
        }
    }
}

// ---------------------------------------------------------------------------
// K3: per row: exact fp32 logits for candidates (wave-parallel), softmax,
//     sparse weighted sum
// ---------------------------------------------------------------------------
__global__ __launch_bounds__(256) void finalize_rows(const float* __restrict__ x,
                                                     const float* __restrict__ dset,
                                                     const int* __restrict__ cidx,
                                                     const int* __restrict__ ccnt,
                                                     float* __restrict__ out) {
    const int n = blockIdx.x;
    const int tid = threadIdx.x;
    const int w = tid >> 6, l = tid & 63;
    int cnt = ccnt[n]; if (cnt > CAND_CAP) cnt = CAND_CAP;

    __shared__ float L[CAND_CAP];
    const float4* xr4 = (const float4*)(x + (size_t)n * K_D);

    // wave w handles candidates w, w+4, ... (no per-candidate barriers)
    for (int c = w; c < cnt; c += 4) {
        const float4* dr4 = (const float4*)(dset + (size_t)cidx[n * CAND_CAP + c] * K_D);
        float p = 0.f;
        for (int j = l; j < K_D / 4; j += 64) {      // 12 iters
            float4 a = xr4[j], b = dr4[j];
            p += a.x * b.x + a.y * b.y + a.z * b.z + a.w * b.w;
        }
#pragma unroll
        for (int off = 32; off > 0; off >>= 1) p += __shfl_down(p, off);
        if (l == 0) L[c] = 4.0f * p;                 // logit = dot / noise_var
    }
    __syncthreads();

    // softmax over candidates (cnt tiny; L becomes weights)
    if (tid == 0) {
        float mx = -3.0e38f;
        for (int c = 0; c < cnt; ++c) mx = fmaxf(mx, L[c]);
        float s = 0.f;
        for (int c = 0; c < cnt; ++c) { float e = expf(L[c] - mx); L[c] = e; s += e; }
        float inv = 1.0f / s;
        for (int c = 0; c < cnt; ++c) L[c] *= inv;
    }
    __syncthreads();

    // out[n][:] = sum_c w_c * dataset[cand_c][:]
    float4* out4 = (float4*)(out + (size_t)n * K_D);
    for (int j = tid; j < K_D / 4; j += 256) {
        float4 o = {0.f, 0.f, 0.f, 0.f};
        for (int c = 0; c < cnt; ++c) {
            float wc = L[c];
            float4 d = *(const float4*)(dset + (size_t)cidx[n * CAND_CAP + c] * K_D + j * 4);
            o.x += wc * d.x; o.y += wc * d.y; o.z += wc * d.z; o.w += wc * d.w;
        }
        out4[j] = o;
    }
}

// ---------------------------------------------------------------------------
extern "C" void kernel_launch(void* const* d_in, const int* in_sizes, int n_in,
                              void* d_out, int out_size, void* d_ws, size_t ws_size,
                              hipStream_t stream) {
    const float* x = (const float*)d_in[0];      // [256,3,32,32]
    const float* dset = (const float*)d_in[1];   // [50000,3,32,32]
    float* out = (float*)d_out;

    // workspace layout (all offsets 256B-aligned):
    //   xb        : 256*3072 bf16   = 1,572,864 B
    //   scores    : 256*50000 fp32  = 51,200,000 B
    //   rowmax_u  : 256 uint        = 1,024 B
    //   cidx      : 256*128 int     = 131,072 B
    //   ccnt      : 256 int         = 1,024 B
    char* ws = (char*)d_ws;
    short* xb          = (short*)ws;
    float* scores      = (float*)(ws + 1572864);
    unsigned* rowmax_u = (unsigned*)(ws + 1572864 + 51200000);
    int* cidx          = (int*)(ws + 1572864 + 51200000 + 1024);
    int* ccnt          = (int*)(ws + 1572864 + 51200000 + 1024 + 131072);

    cvt_x_kernel<<<768, 256, 0, stream>>>(x, xb, rowmax_u, ccnt);
    gemm_scores<<<(M_D + MT - 1) / MT, 256, 0, stream>>>(xb, dset, scores, rowmax_u);
    collect_kernel<<<N_Q * SPLIT, 256, 0, stream>>>(scores, rowmax_u, cidx, ccnt);
    finalize_rows<<<N_Q, 256, 0, stream>>>(x, dset, cidx, ccnt, out);
}

// Round 6
// 1016.717 us; speedup vs baseline: 1.1959x; 1.1955x over previous
//
#include <hip/hip_runtime.h>
#include <stdint.h>
#include <stddef.h>

// Problem constants
#define N_Q 256        // queries
#define M_D 50000      // dataset rows
#define K_D 3072       // feature dim
#define MT 64          // dataset rows (output cols) per workgroup in scores GEMM
#define BK 32          // K elements per step
#define NKT 96         // K steps
#define RING 5         // B LDS ring depth (stage t+3 while reading t; 1 barrier/iter)
#define CAND_CAP 128   // max candidates per row
#define WINDOW 9.0f    // raw-score candidate window (36 logits; bf16 err bound ~0.6)
#define SPLIT 8        // scan blocks per score row

typedef short bf16x8 __attribute__((ext_vector_type(8)));   // 8 bf16 = 4 VGPRs
typedef float f32x4 __attribute__((ext_vector_type(4)));

// fp32 -> bf16 round-to-nearest-even (bitwise identical to prior rounds)
static __device__ __forceinline__ unsigned short f2bf(float f) {
    unsigned int u = __float_as_uint(f);
    u += 0x7fffu + ((u >> 16) & 1u);
    return (unsigned short)(u >> 16);
}

// monotone float -> sortable uint (for atomicMax on float values)
static __device__ __forceinline__ unsigned fkey(float f) {
    int i = __float_as_int(f);
    return (i < 0) ? ~(unsigned)i : ((unsigned)i | 0x80000000u);
}
static __device__ __forceinline__ float funkey(unsigned u) {
    int i = (u & 0x80000000u) ? (int)(u & 0x7fffffffu) : ~(int)u;
    return __int_as_float(i);
}

// async global->LDS, 16B/lane; LDS dest = wave-uniform base + lane*16 (m104)
static __device__ __forceinline__ void load_lds16(const void* g, void* l) {
    __builtin_amdgcn_global_load_lds(
        (const __attribute__((address_space(1))) void*)g,
        (__attribute__((address_space(3))) void*)l, 16, 0, 0);
}

// pinned-issue 16B global load (volatile asm: compiler cannot sink/hoist it,
// so our hand-counted vmcnt immediates stay exact — round-3 lesson)
static __device__ __forceinline__ bf16x8 gload_a(const short* p) {
    bf16x8 r;
    asm volatile("global_load_dwordx4 %0, %1, off" : "=v"(r) : "v"(p) : "memory");
    return r;
}

// counted wait: vmcnt(N), then fence the scheduler (rule #18: MFMA is not a
// memory op, "memory" clobber alone does not order it past the wait)
#define WAITV(N)                                                     \
    do {                                                             \
        __builtin_amdgcn_sched_barrier(0);                           \
        asm volatile("s_waitcnt vmcnt(" #N ")" ::: "memory");        \
        __builtin_amdgcn_sched_barrier(0);                           \
    } while (0)

// ---------------------------------------------------------------------------
// K0: convert x [256x3072] fp32 -> bf16; also zero rowmax keys + cand counts
// ---------------------------------------------------------------------------
__global__ __launch_bounds__(256) void cvt_x_kernel(const float* __restrict__ x,
                                                    short* __restrict__ xb,
                                                    unsigned* __restrict__ rowmax_u,
                                                    int* __restrict__ ccnt) {
    int i = (blockIdx.x * 256 + threadIdx.x) * 4;   // grid covers exactly 786432
    float4 f = *(const float4*)(x + i);
    ushort4 o;
    o.x = f2bf(f.x); o.y = f2bf(f.y); o.z = f2bf(f.z); o.w = f2bf(f.w);
    *(ushort4*)(xb + i) = o;
    if (blockIdx.x == 0) {
        rowmax_u[threadIdx.x] = 0u;   // smallest key; set by gemm atomicMax
        ccnt[threadIdx.x] = 0;
    }
}

// ---------------------------------------------------------------------------
// K1: scores[n][m] = sum_k xb[n][k] * bf16(dataset[m][k])
// Counted-vmcnt ring pipeline (T4):
//   - B (dset fp32, HBM-cold, read ONCE): depth-5 LDS ring, 2 gload_lds/wave
//     per step (each = 64 lanes x 16B = 1KB in flight, ZERO VGPR), staged 3
//     steps ahead; consumed after `s_waitcnt vmcnt(8)` (never 0) + s_barrier.
//     In-flight per CU ~= 12 waves x 6 x 1KB = 72KB >> 8KB needed for 10B/cyc.
//   - A (xb bf16, 1.5MB, L2-resident): fragments read straight from L2 into
//     regs via pinned volatile-asm loads, double-buffered (aE/aO), 2 ahead.
//   - vmcnt queue per iter t (issue order): ... B(t+1), A(t), B(t+2), A(t+1),
//     B(t+3) -> newer-than-A(t) = 2+4+2 = 8 -> vmcnt(8) guarantees A(t), B(t).
//     Tail peeled with 8/6/4/0. Ring-5: write slot of t+3 last held t-2,
//     whose ds_reads completed before the barrier all waves already passed.
//   - B frag reads XOR-swizzled (slot = chunk ^ (row&7), staged pre-swizzled
//     at the SOURCE per rule #21) -> 2-way bank conflicts (free).
// fp32->bf16 RNE convert at frag-read; accumulation order identical to all
// prior rounds -> scores bitwise identical (absmax 0.015625 preserved).
// Fused per-row max epilogue (shfl_xor + sortable-uint atomicMax).
// ---------------------------------------------------------------------------
__global__ __launch_bounds__(256, 3) void gemm_scores(const short* __restrict__ xb,
                                                      const float* __restrict__ dset,
                                                      float* __restrict__ scores,
                                                      unsigned* __restrict__ rowmax_u) {
    __shared__ __align__(16) float sB[RING * MT * BK];   // 5 x 8KB = 40KB

    const int tid = threadIdx.x;
    const int w = tid >> 6;        // wave 0..3: output rows w*64..w*64+63
    const int l = tid & 63;
    const int m0 = blockIdx.x * MT;

    // ---- B staging: chunk id = g*256+tid (g=0..1); row R=id>>3, slot S=id&7,
    //      source chunk C = S ^ (R&7). Rows clamped at M edge (uniform, cheap).
    const int bR = tid >> 3;                       // 0..31 (g=0)
    const int bC = (tid & 7) ^ (bR & 7);
    int br0 = m0 + bR;      if (br0 >= M_D) br0 = M_D - 1;
    int br1 = m0 + bR + 32; if (br1 >= M_D) br1 = M_D - 1;
    const float* bSrc0 = dset + (size_t)br0 * K_D + bC * 4;
    const float* bSrc1 = dset + (size_t)br1 * K_D + bC * 4;

    auto stageB = [&](int slot, int kt) {
        load_lds16(bSrc0 + kt * 32, &sB[slot * 2048 + w * 256]);
        load_lds16(bSrc1 + kt * 32, &sB[slot * 2048 + 1024 + w * 256]);
    };

    // ---- A fragment pointers (straight from L2; layout identical to r3)
    const int rA = l & 15;         // fragment row-within-16
    const int kq = l >> 4;         // lane's k-chunk (k offset kq*8)
    const short* pA[4];
#pragma unroll
    for (int ai = 0; ai < 4; ++ai)
        pA[ai] = xb + (size_t)(w * 64 + ai * 16 + rA) * K_D + kq * 8;

    // ---- B fragment read offsets (swizzled; same formulas as r5, verified)
    const int bOff0 = rA * 32 + (((2 * kq)     ^ (rA & 7)) << 2);
    const int bOff1 = rA * 32 + (((2 * kq + 1) ^ (rA & 7)) << 2);

    f32x4 acc[4][4];
#pragma unroll
    for (int i = 0; i < 4; ++i)
#pragma unroll
        for (int j = 0; j < 4; ++j)
            acc[i][j] = (f32x4){0.f, 0.f, 0.f, 0.f};

    auto compute = [&](int slot, const bf16x8* av) {
        const float* base = &sB[slot * 2048];
        bf16x8 bfr[4];
#pragma unroll
        for (int bj = 0; bj < 4; ++bj) {
            float4 lo = *(const float4*)&base[bj * 512 + bOff0];
            float4 hi = *(const float4*)&base[bj * 512 + bOff1];
            bf16x8 q;
            q[0] = (short)f2bf(lo.x); q[1] = (short)f2bf(lo.y);
            q[2] = (short)f2bf(lo.z); q[3] = (short)f2bf(lo.w);
            q[4] = (short)f2bf(hi.x); q[5] = (short)f2bf(hi.y);
            q[6] = (short)f2bf(hi.z); q[7] = (short)f2bf(hi.w);
            bfr[bj] = q;
        }
#pragma unroll
        for (int ai = 0; ai < 4; ++ai)
#pragma unroll
            for (int bj = 0; bj < 4; ++bj)
                acc[ai][bj] = __builtin_amdgcn_mfma_f32_16x16x32_bf16(
                    av[ai], bfr[bj], acc[ai][bj], 0, 0, 0);
    };

    bf16x8 aE[4], aO[4];

    // ---- prologue: issue order B0, B1, A0, B2, A1 (matches steady-state queue)
    stageB(0, 0);
    stageB(1, 1);
#pragma unroll
    for (int ai = 0; ai < 4; ++ai) aE[ai] = gload_a(pA[ai]);            // A(0)
    stageB(2, 2);
#pragma unroll
    for (int ai = 0; ai < 4; ++ai) aO[ai] = gload_a(pA[ai] + 32);       // A(1)

    int sR = 0;                    // ring slot of step t
    for (int t = 0; t < 92; t += 2) {
        {   // even iter t: consume B[sR], aE=A(t)
            int sw = sR + 3; if (sw >= RING) sw -= RING;
            stageB(sw, t + 3);
            WAITV(8);
            __builtin_amdgcn_s_barrier();
            compute(sR, aE);
#pragma unroll
            for (int ai = 0; ai < 4; ++ai)
                aE[ai] = gload_a(pA[ai] + (t + 2) * 32);                // A(t+2)
            if (++sR == RING) sR = 0;
        }
        {   // odd iter t+1: consume B[sR], aO=A(t+1)
            int sw = sR + 3; if (sw >= RING) sw -= RING;
            stageB(sw, t + 4);
            WAITV(8);
            __builtin_amdgcn_s_barrier();
            compute(sR, aO);
#pragma unroll
            for (int ai = 0; ai < 4; ++ai)
                aO[ai] = gload_a(pA[ai] + (t + 3) * 32);                // A(t+3)
            if (++sR == RING) sR = 0;
        }
    }
    {   // t=92 (even): last stage (B95), still steady-state count
        int sw = sR + 3; if (sw >= RING) sw -= RING;
        stageB(sw, 95);
        WAITV(8);
        __builtin_amdgcn_s_barrier();
        compute(sR, aE);
#pragma unroll
        for (int ai = 0; ai < 4; ++ai) aE[ai] = gload_a(pA[ai] + 94 * 32);
        if (++sR == RING) sR = 0;
    }
    {   // t=93 (odd): newer-than-A(93) = B(95)+A(94) = 6
        WAITV(6);
        __builtin_amdgcn_s_barrier();
        compute(sR, aO);
#pragma unroll
        for (int ai = 0; ai < 4; ++ai) aO[ai] = gload_a(pA[ai] + 95 * 32);
        if (++sR == RING) sR = 0;
    }
    {   // t=94 (even): newer-than-A(94) = A(95) = 4
        WAITV(4);
        __builtin_amdgcn_s_barrier();
        compute(sR, aE);
        if (++sR == RING) sR = 0;
    }
    {   // t=95 (odd): drain
        WAITV(0);
        __builtin_amdgcn_s_barrier();
        compute(sR, aO);
    }

    // ---- fused per-row max: reduce over bj + 16 column lanes, atomicMax key
    const int crow = (l >> 4) * 4;
    const int ccol = l & 15;
#pragma unroll
    for (int ai = 0; ai < 4; ++ai) {
#pragma unroll
        for (int r = 0; r < 4; ++r) {
            float mx = -3.0e38f;
#pragma unroll
            for (int bj = 0; bj < 4; ++bj) {
                float v = acc[ai][bj][r];
                if ((m0 + bj * 16 + ccol) < M_D) mx = fmaxf(mx, v);
            }
#pragma unroll
            for (int off = 1; off < 16; off <<= 1)
                mx = fmaxf(mx, __shfl_xor(mx, off));
            if (ccol == 0)
                atomicMax(rowmax_u + (w * 64 + ai * 16 + crow + r), fkey(mx));
        }
    }

    // ---- store scores: C/D layout col = l&15, row = (l>>4)*4 + r [m89]
#pragma unroll
    for (int ai = 0; ai < 4; ++ai) {
#pragma unroll
        for (int bj = 0; bj < 4; ++bj) {
            int m = m0 + bj * 16 + ccol;
            if (m < M_D) {
#pragma unroll
                for (int r = 0; r < 4; ++r) {
                    int n = w * 64 + ai * 16 + crow + r;
                    scores[(size_t)n * M_D + m] = acc[ai][bj][r];
                }
            }
        }
    }
}

// ---------------------------------------------------------------------------
// K2: per (row, segment): collect candidates with s >= rowmax - WINDOW
// ---------------------------------------------------------------------------
__global__ __launch_bounds__(256) void collect_kernel(const float* __restrict__ scores,
                                                      const unsigned* __restrict__ rowmax_u,
                                                      int* __restrict__ cidx,
                                                      int* __restrict__ ccnt) {
    const int n = blockIdx.x >> 3;
    const int s = blockIdx.x & 7;
    const int tid = threadIdx.x;

    const float thr = funkey(rowmax_u[n]) - WINDOW;

    const float4* row4 = (const float4*)(scores + (size_t)n * M_D);
    const int start = s * 1563;                 // 1563*8 = 12504 >= 12500
    int end = start + 1563; if (end > M_D / 4) end = M_D / 4;

    for (int i = start + tid; i < end; i += 256) {
        float4 v = row4[i];
        if (v.x >= thr || v.y >= thr || v.z >= thr || v.w >= thr) {
            float e[4] = {v.x, v.y, v.z, v.w};
#pragma unroll
            for (int j = 0; j < 4; ++j) {
                if (e[j] >= thr) {
                    int p = atomicAdd(&ccnt[n], 1);   // rare (~1-5/row)
                    if (p < CAND_CAP) cidx[n * CAND_CAP + p] = i * 4 + j;
                }
            }
        }
    }
}

// ---------------------------------------------------------------------------
// K3: per row: exact fp32 logits for candidates (wave-parallel), softmax,
//     sparse weighted sum
// ---------------------------------------------------------------------------
__global__ __launch_bounds__(256) void finalize_rows(const float* __restrict__ x,
                                                     const float* __restrict__ dset,
                                                     const int* __restrict__ cidx,
                                                     const int* __restrict__ ccnt,
                                                     float* __restrict__ out) {
    const int n = blockIdx.x;
    const int tid = threadIdx.x;
    const int w = tid >> 6, l = tid & 63;
    int cnt = ccnt[n]; if (cnt > CAND_CAP) cnt = CAND_CAP;

    __shared__ float L[CAND_CAP];
    const float4* xr4 = (const float4*)(x + (size_t)n * K_D);

    // wave w handles candidates w, w+4, ... (no per-candidate barriers)
    for (int c = w; c < cnt; c += 4) {
        const float4* dr4 = (const float4*)(dset + (size_t)cidx[n * CAND_CAP + c] * K_D);
        float p = 0.f;
        for (int j = l; j < K_D / 4; j += 64) {      // 12 iters
            float4 a = xr4[j], b = dr4[j];
            p += a.x * b.x + a.y * b.y + a.z * b.z + a.w * b.w;
        }
#pragma unroll
        for (int off = 32; off > 0; off >>= 1) p += __shfl_down(p, off);
        if (l == 0) L[c] = 4.0f * p;                 // logit = dot / noise_var
    }
    __syncthreads();

    // softmax over candidates (cnt tiny; L becomes weights)
    if (tid == 0) {
        float mx = -3.0e38f;
        for (int c = 0; c < cnt; ++c) mx = fmaxf(mx, L[c]);
        float s = 0.f;
        for (int c = 0; c < cnt; ++c) { float e = expf(L[c] - mx); L[c] = e; s += e; }
        float inv = 1.0f / s;
        for (int c = 0; c < cnt; ++c) L[c] *= inv;
    }
    __syncthreads();

    // out[n][:] = sum_c w_c * dataset[cand_c][:]
    float4* out4 = (float4*)(out + (size_t)n * K_D);
    for (int j = tid; j < K_D / 4; j += 256) {
        float4 o = {0.f, 0.f, 0.f, 0.f};
        for (int c = 0; c < cnt; ++c) {
            float wc = L[c];
            float4 d = *(const float4*)(dset + (size_t)cidx[n * CAND_CAP + c] * K_D + j * 4);
            o.x += wc * d.x; o.y += wc * d.y; o.z += wc * d.z; o.w += wc * d.w;
        }
        out4[j] = o;
    }
}

// ---------------------------------------------------------------------------
extern "C" void kernel_launch(void* const* d_in, const int* in_sizes, int n_in,
                              void* d_out, int out_size, void* d_ws, size_t ws_size,
                              hipStream_t stream) {
    const float* x = (const float*)d_in[0];      // [256,3,32,32]
    const float* dset = (const float*)d_in[1];   // [50000,3,32,32]
    float* out = (float*)d_out;

    // workspace layout (all offsets 256B-aligned):
    //   xb        : 256*3072 bf16   = 1,572,864 B
    //   scores    : 256*50000 fp32  = 51,200,000 B
    //   rowmax_u  : 256 uint        = 1,024 B
    //   cidx      : 256*128 int     = 131,072 B
    //   ccnt      : 256 int         = 1,024 B
    char* ws = (char*)d_ws;
    short* xb          = (short*)ws;
    float* scores      = (float*)(ws + 1572864);
    unsigned* rowmax_u = (unsigned*)(ws + 1572864 + 51200000);
    int* cidx          = (int*)(ws + 1572864 + 51200000 + 1024);
    int* ccnt          = (int*)(ws + 1572864 + 51200000 + 1024 + 131072);

    cvt_x_kernel<<<768, 256, 0, stream>>>(x, xb, rowmax_u, ccnt);
    gemm_scores<<<(M_D + MT - 1) / MT, 256, 0, stream>>>(xb, dset, scores, rowmax_u);
    collect_kernel<<<N_Q * SPLIT, 256, 0, stream>>>(scores, rowmax_u, cidx, ccnt);
    finalize_rows<<<N_Q, 256, 0, stream>>>(x, dset, cidx, ccnt, out);
}